// Round 1
// baseline (422.321 us; speedup 1.0000x reference)
//
#include <hip/hip_runtime.h>
#include <cstdint>

// DynMoleRouterLoss: gate_logits [N x 64] f32, attention_mask [maskN] i32 -> scalar f32.
// Strategy: thread-per-row (64 experts in regs). Common case has row entropy > 1.5
// so routing_w == orig_w; rare low-entropy rows produce "corrections" via atomics.
// acc layout in d_ws (floats): [0..63] orig per-expert sums (m-weighted),
// [64..127] corrections (masked-out contributions), [128] sum(clip), [129] sum(clip^q).

static constexpr float LOG2E = 1.4426950408889634f;
static constexpr float LEPS  = -16.609640474436812f;   // log2(1e-5)
static constexpr float QQ    = 1.2f;

__global__ void zero_acc(float* __restrict__ a) {
    if (threadIdx.x < 130) a[threadIdx.x] = 0.f;
}

__global__ __launch_bounds__(64, 4)
void moe_main(const float* __restrict__ G, const int* __restrict__ am,
              long long N, int maskN, int maskPow2, float* __restrict__ acc) {
    __shared__ float tile[64][68];          // 68 pad: conflict-free writes (b128) + column reads
    const int lane = threadIdx.x;           // one wave per block
    const long long stride = (long long)gridDim.x * 64;

    float clip_acc = 0.f, clipq_acc = 0.f, col_acc = 0.f;

    for (long long base = (long long)blockIdx.x * 64; base < N; base += stride) {
        long long row = base + lane;
        bool valid = row < N;
        float mscale = 0.f;
        float rc = 0.f, rcq = 0.f;
        bool flag = false;
        float t[64];

        if (valid) {
            int mi = maskPow2 ? (int)(row & (long long)(maskN - 1)) : (int)(row % (long long)maskN);
            mscale = (float)am[mi];

            const float4* rp = (const float4*)(G + row * 64);
            #pragma unroll
            for (int k = 0; k < 16; ++k) {
                float4 v = rp[k];
                t[4*k+0] = v.x; t[4*k+1] = v.y; t[4*k+2] = v.z; t[4*k+3] = v.w;
            }
            float mx = -3.402823466e38f;
            #pragma unroll
            for (int i = 0; i < 64; ++i) mx = fmaxf(mx, t[i]);
            float z = 0.f;
            #pragma unroll
            for (int i = 0; i < 64; ++i) {
                float tt = (t[i] - mx) * LOG2E;   // log2 of unnormalized softmax numerator
                t[i] = tt;
                z += exp2f(tt);
            }
            float lz = log2f(z);
            #pragma unroll
            for (int i = 0; i < 64; ++i) {
                float u  = fmaxf(t[i] - lz, LEPS);  // log2(clip(w, 1e-5)); clip ~never binds here
                float c  = exp2f(u);
                float cq = exp2f(QQ * u);
                rc += c; rcq += cq;
                t[i] = c;                           // t now holds clipped prob (== w in practice)
            }
            clip_acc += rc; clipq_acc += rcq;
            if (mscale != 0.f) {
                // row Tsallis entropy: (1 - sum((c/rc)^q)) / (q-1) = (1 - rcq * rc^-q) * 5
                float ent = (1.f - rcq * exp2f(-QQ * log2f(rc))) * 5.f;
                flag = ent < 1.5f;                  // rare: row participates in top-p masking
            }
        }

        // write m-weighted probs into tile (row = lane), zeros for invalid rows
        if (valid) {
            #pragma unroll
            for (int k = 0; k < 16; ++k) {
                float4 w4 = make_float4(t[4*k+0]*mscale, t[4*k+1]*mscale,
                                        t[4*k+2]*mscale, t[4*k+3]*mscale);
                *(float4*)&tile[lane][4*k] = w4;
            }
        } else {
            float4 z4 = make_float4(0.f, 0.f, 0.f, 0.f);
            #pragma unroll
            for (int k = 0; k < 16; ++k) *(float4*)&tile[lane][4*k] = z4;
        }
        __syncthreads();

        // column accumulate: lane == expert
        float cs = 0.f;
        #pragma unroll
        for (int r = 0; r < 64; ++r) cs += tile[r][lane];
        col_acc += cs;

        // rare path: wave-cooperative top-p mask for flagged rows (tile row holds w, m==1)
        unsigned long long bal = __ballot(flag ? 1 : 0);
        while (bal) {
            int r = __ffsll((unsigned long long)bal) - 1;
            bal &= bal - 1;
            float wl = tile[r][lane];
            int rank = 0; float cum = 0.f;
            for (int j = 0; j < 64; ++j) {
                float wj = tile[r][j];                       // broadcast read
                bool before = (wj > wl) || (wj == wl && j < lane);  // stable desc sort order
                rank += before ? 1 : 0;
                cum  += (before || j == lane) ? wj : 0.f;
            }
            if (cum > 0.75f && rank >= 2) atomicAdd(&acc[64 + lane], wl);
        }
        __syncthreads();
    }

    // epilogue: reduce scalars across wave, one atomic per lane for experts
    #pragma unroll
    for (int s = 32; s >= 1; s >>= 1) {
        clip_acc  += __shfl_xor(clip_acc,  s, 64);
        clipq_acc += __shfl_xor(clipq_acc, s, 64);
    }
    atomicAdd(&acc[lane], col_acc);
    if (lane == 0) {
        atomicAdd(&acc[128], clip_acc);
        atomicAdd(&acc[129], clipq_acc);
    }
}

__global__ void finalize(const float* __restrict__ acc, const int* __restrict__ am,
                         int maskN, int layers, float* __restrict__ out) {
    __shared__ float red[256];
    int t = threadIdx.x;

    float ms = 0.f;
    for (int i = t; i < maskN; i += 256) ms += (float)am[i];
    red[t] = ms; __syncthreads();
    for (int s = 128; s >= 1; s >>= 1) { if (t < s) red[t] += red[t+s]; __syncthreads(); }
    float denom = red[0] * (float)layers;
    __syncthreads();

    float p = 0.f;
    if (t < 64) {
        float o   = acc[t];
        float tok = o - acc[64 + t];
        p = tok * o;
    }
    red[t] = p; __syncthreads();
    for (int s = 128; s >= 1; s >>= 1) { if (t < s) red[t] += red[t+s]; __syncthreads(); }

    if (t == 0) {
        float lb   = 64.f * red[0] / (denom * denom);
        float clip = acc[128], clipq = acc[129];
        float ent  = (1.f - clipq * exp2f(-QQ * log2f(clip))) * 5.f;
        out[0] = 1e-3f * ent + 1e-3f * lb;
    }
}

extern "C" void kernel_launch(void* const* d_in, const int* in_sizes, int n_in,
                              void* d_out, int out_size, void* d_ws, size_t ws_size,
                              hipStream_t stream) {
    const float* G  = (const float*)d_in[0];
    const int*   am = (const int*)d_in[1];
    long long NE = in_sizes[0];
    long long N  = NE / 64;                 // rows
    int maskN    = in_sizes[1];             // batch*seq
    int layers   = (int)(N / (long long)maskN);
    int maskPow2 = ((maskN & (maskN - 1)) == 0) ? 1 : 0;
    float* acc = (float*)d_ws;              // 130 floats

    hipLaunchKernelGGL(zero_acc, dim3(1), dim3(256), 0, stream, acc);
    hipLaunchKernelGGL(moe_main, dim3(2048), dim3(64), 0, stream,
                       G, am, N, maskN, maskPow2, acc);
    hipLaunchKernelGGL(finalize, dim3(1), dim3(256), 0, stream,
                       acc, am, maskN, layers, (float*)d_out);
}

// Round 2
// 415.336 us; speedup vs baseline: 1.0168x; 1.0168x over previous
//
#include <hip/hip_runtime.h>
#include <cstdint>

// DynMoleRouterLoss: gate_logits [N x 64] f32, attention_mask [maskN] i32 -> scalar f32.
// Coalesced layout: 16 lanes per row, each thread owns experts 4*(t%16)..+3 of row t/16.
// Row reductions via width-16 shfl_xor butterflies; per-expert sums live in 4 regs/thread
// (expert set fixed per lane). Rare low-entropy rows (top-p masking) handled by a
// 16-lane-group sort-rank path with atomics into a correction buffer (screened, ~never taken).
// acc layout in d_ws (floats): [0..63] m-weighted orig per-expert sums, [64..127] corrections,
// [128] sum(clip(w)), [129] sum(clip(w)^1.2).

static constexpr float LOG2E = 1.4426950408889634f;
static constexpr float EPS   = 1e-5f;
static constexpr float EPSQ  = 1e-6f;     // (1e-5)^1.2
static constexpr float QQ    = 1.2f;

__global__ void zero_acc(float* __restrict__ a) {
    if (threadIdx.x < 130) a[threadIdx.x] = 0.f;
}

__global__ __launch_bounds__(256)
void moe_main(const float* __restrict__ G, const int* __restrict__ am,
              long long N, int maskN, int maskPow2, float* __restrict__ acc)
{
    __shared__ float sm[4][66];
    const int t    = threadIdx.x;
    const int lane = t & 63;
    const int wv   = t >> 6;
    const int s    = lane & 15;   // expert quad: experts 4s..4s+3
    const int grp  = lane >> 4;   // row slot within wave
    const long long tiles = (N + 15) >> 4;

    float ea0 = 0.f, ea1 = 0.f, ea2 = 0.f, ea3 = 0.f;   // per-expert m-weighted sums
    float clipA = 0.f, clipqA = 0.f;

    for (long long tile = blockIdx.x; tile < tiles; tile += gridDim.x) {
        long long row = (tile << 4) + (t >> 4);
        bool valid = row < N;
        float w0=0.f,w1=0.f,w2=0.f,w3=0.f;
        float c0=0.f,c1=0.f,c2=0.f,c3=0.f;
        float mscale = 0.f, rcq = 0.f;

        if (valid) {
            int mi = maskPow2 ? (int)(row & (long long)(maskN - 1))
                              : (int)(row % (long long)maskN);
            mscale = (float)am[mi];

            float4 v = *(const float4*)(G + (row << 6) + (s << 2));

            float mx = fmaxf(fmaxf(v.x, v.y), fmaxf(v.z, v.w));
            #pragma unroll
            for (int sh = 1; sh < 16; sh <<= 1) mx = fmaxf(mx, __shfl_xor(mx, sh, 16));

            float mxl = mx * LOG2E;
            float t0 = __fmaf_rn(v.x, LOG2E, -mxl);
            float t1 = __fmaf_rn(v.y, LOG2E, -mxl);
            float t2 = __fmaf_rn(v.z, LOG2E, -mxl);
            float t3 = __fmaf_rn(v.w, LOG2E, -mxl);
            float x0 = __builtin_amdgcn_exp2f(t0);
            float x1 = __builtin_amdgcn_exp2f(t1);
            float x2 = __builtin_amdgcn_exp2f(t2);
            float x3 = __builtin_amdgcn_exp2f(t3);

            float z = (x0 + x1) + (x2 + x3);
            #pragma unroll
            for (int sh = 1; sh < 16; sh <<= 1) z += __shfl_xor(z, sh, 16);

            float rz = 1.0f / z;
            float lz = __builtin_amdgcn_logf(z);          // log2(z)
            float zq = __builtin_amdgcn_exp2f(-QQ * lz);  // z^-1.2

            w0 = x0 * rz; w1 = x1 * rz; w2 = x2 * rz; w3 = x3 * rz;
            c0 = fmaxf(w0, EPS); c1 = fmaxf(w1, EPS);
            c2 = fmaxf(w2, EPS); c3 = fmaxf(w3, EPS);
            float q0 = fmaxf(__builtin_amdgcn_exp2f(QQ * t0) * zq, EPSQ);
            float q1 = fmaxf(__builtin_amdgcn_exp2f(QQ * t1) * zq, EPSQ);
            float q2 = fmaxf(__builtin_amdgcn_exp2f(QQ * t2) * zq, EPSQ);
            float q3 = fmaxf(__builtin_amdgcn_exp2f(QQ * t3) * zq, EPSQ);

            clipA  += (c0 + c1) + (c2 + c3);
            float rq = (q0 + q1) + (q2 + q3);
            clipqA += rq;
            #pragma unroll
            for (int sh = 1; sh < 16; sh <<= 1) rq += __shfl_xor(rq, sh, 16);
            rcq = rq;                                     // row sum of clip(w)^q

            ea0 = __fmaf_rn(w0, mscale, ea0);
            ea1 = __fmaf_rn(w1, mscale, ea1);
            ea2 = __fmaf_rn(w2, mscale, ea2);
            ea3 = __fmaf_rn(w3, mscale, ea3);
        }

        // rare path screen: flag requires rcq >= 0.7 * rc^1.2, and rc >= sum(w) ~= 1
        bool pre = valid && (mscale != 0.f) && (rcq >= 0.699f);
        unsigned long long balpre = __ballot(pre ? 1 : 0);
        if (balpre) {
            float rc = (c0 + c1) + (c2 + c3);
            #pragma unroll
            for (int sh = 1; sh < 16; sh <<= 1) rc += __shfl_xor(rc, sh, 16);
            float ent = (1.f - rcq * __builtin_amdgcn_exp2f(-QQ * __builtin_amdgcn_logf(rc))) * 5.f;
            bool flag = pre && (ent < 1.5f);
            unsigned long long bal = __ballot(flag ? 1 : 0);
            #pragma unroll 1
            for (int g = 0; g < 4; ++g) {
                if ((bal >> (g * 16)) & 0xFFFFull) {
                    if (grp == g) {
                        float wl[4] = {w0, w1, w2, w3};
                        int   rank[4] = {0, 0, 0, 0};
                        float cum[4]  = {wl[0], wl[1], wl[2], wl[3]};
                        int base4 = s << 2;
                        #pragma unroll 1
                        for (int j = 0; j < 16; ++j) {
                            float uj[4];
                            uj[0] = __shfl(w0, j, 16);
                            uj[1] = __shfl(w1, j, 16);
                            uj[2] = __shfl(w2, j, 16);
                            uj[3] = __shfl(w3, j, 16);
                            for (int m = 0; m < 4; ++m) {
                                int ej = (j << 2) + m;
                                #pragma unroll
                                for (int k = 0; k < 4; ++k) {
                                    int ek = base4 + k;
                                    bool before = (uj[m] > wl[k]) || (uj[m] == wl[k] && ej < ek);
                                    if (before) { rank[k]++; cum[k] += uj[m]; }
                                }
                            }
                        }
                        #pragma unroll
                        for (int k = 0; k < 4; ++k)
                            if (cum[k] > 0.75f && rank[k] >= 2)
                                atomicAdd(&acc[64 + base4 + k], wl[k]);   // mscale==1 here
                    }
                }
            }
        }
    }

    // reduce per-expert sums across the 4 row-groups of each wave
    ea0 += __shfl_xor(ea0, 16, 64); ea0 += __shfl_xor(ea0, 32, 64);
    ea1 += __shfl_xor(ea1, 16, 64); ea1 += __shfl_xor(ea1, 32, 64);
    ea2 += __shfl_xor(ea2, 16, 64); ea2 += __shfl_xor(ea2, 32, 64);
    ea3 += __shfl_xor(ea3, 16, 64); ea3 += __shfl_xor(ea3, 32, 64);
    #pragma unroll
    for (int sh = 1; sh <= 32; sh <<= 1) {
        clipA  += __shfl_xor(clipA,  sh, 64);
        clipqA += __shfl_xor(clipqA, sh, 64);
    }
    if (grp == 0) {
        sm[wv][(s << 2) + 0] = ea0;
        sm[wv][(s << 2) + 1] = ea1;
        sm[wv][(s << 2) + 2] = ea2;
        sm[wv][(s << 2) + 3] = ea3;
    }
    if (lane == 0) { sm[wv][64] = clipA; sm[wv][65] = clipqA; }
    __syncthreads();
    if (t < 64) {
        float v = (sm[0][t] + sm[1][t]) + (sm[2][t] + sm[3][t]);
        atomicAdd(&acc[t], v);
    }
    if (t == 0) {
        atomicAdd(&acc[128], (sm[0][64] + sm[1][64]) + (sm[2][64] + sm[3][64]));
        atomicAdd(&acc[129], (sm[0][65] + sm[1][65]) + (sm[2][65] + sm[3][65]));
    }
}

__global__ void finalize(const float* __restrict__ acc, const int* __restrict__ am,
                         int maskN, int layers, float* __restrict__ out) {
    __shared__ float red[256];
    int t = threadIdx.x;

    float ms = 0.f;
    for (int i = t; i < maskN; i += 256) ms += (float)am[i];
    red[t] = ms; __syncthreads();
    for (int s = 128; s >= 1; s >>= 1) { if (t < s) red[t] += red[t + s]; __syncthreads(); }
    float denom = red[0] * (float)layers;
    __syncthreads();

    float p = 0.f;
    if (t < 64) {
        float o   = acc[t];
        float tok = o - acc[64 + t];
        p = tok * o;
    }
    red[t] = p; __syncthreads();
    for (int s = 128; s >= 1; s >>= 1) { if (t < s) red[t] += red[t + s]; __syncthreads(); }

    if (t == 0) {
        float lb    = 64.f * red[0] / (denom * denom);
        float clip  = acc[128], clipq = acc[129];
        float ent   = (1.f - clipq * __builtin_amdgcn_exp2f(-QQ * __builtin_amdgcn_logf(clip))) * 5.f;
        out[0] = 1e-3f * ent + 1e-3f * lb;
    }
}

extern "C" void kernel_launch(void* const* d_in, const int* in_sizes, int n_in,
                              void* d_out, int out_size, void* d_ws, size_t ws_size,
                              hipStream_t stream) {
    const float* G  = (const float*)d_in[0];
    const int*   am = (const int*)d_in[1];
    long long NE = in_sizes[0];
    long long N  = NE / 64;
    int maskN    = in_sizes[1];
    int layers   = (int)(N / (long long)maskN);
    int maskPow2 = ((maskN & (maskN - 1)) == 0) ? 1 : 0;
    float* acc = (float*)d_ws;   // 130 floats

    long long tiles = (N + 15) >> 4;
    int grid = (int)(tiles < 1536 ? tiles : 1536);

    hipLaunchKernelGGL(zero_acc, dim3(1), dim3(256), 0, stream, acc);
    hipLaunchKernelGGL(moe_main, dim3(grid), dim3(256), 0, stream,
                       G, am, N, maskN, maskPow2, acc);
    hipLaunchKernelGGL(finalize, dim3(1), dim3(256), 0, stream,
                       acc, am, maskN, layers, (float*)d_out);
}

// Round 3
// 413.914 us; speedup vs baseline: 1.0203x; 1.0034x over previous
//
#include <hip/hip_runtime.h>
#include <cstdint>

// DynMoleRouterLoss: gate_logits [N x 64] f32, attention_mask [maskN] i32 -> scalar f32.
// R3: register ping-pong pipeline. Each thread stages 4 rows' float4 (its expert quad)
// for tile t+1 BEFORE computing tile t -> 4KB/wave in flight, HBM latency hidden under
// ~840 cyc of compute. 16 lanes per row; width-16 shfl butterflies for row reductions.
// acc layout in d_ws (floats): [0..63] m-weighted orig per-expert sums, [64..127]
// top-p corrections (rare), [128] sum(clip(w)), [129] sum(clip(w)^1.2).

static constexpr float LOG2E = 1.4426950408889634f;
static constexpr float EPS   = 1e-5f;
static constexpr float EPSQ  = 1e-6f;     // (1e-5)^1.2
static constexpr float QQ    = 1.2f;

__global__ void zero_acc(float* __restrict__ a) {
    if (threadIdx.x < 130) a[threadIdx.x] = 0.f;
}

__device__ __forceinline__
void pass_row(float4 v, float msc, bool valid, int s, int grp,
              float& ea0, float& ea1, float& ea2, float& ea3,
              float& clipA, float& clipqA, float* __restrict__ acc)
{
    float mx = fmaxf(fmaxf(v.x, v.y), fmaxf(v.z, v.w));
    #pragma unroll
    for (int sh = 1; sh < 16; sh <<= 1) mx = fmaxf(mx, __shfl_xor(mx, sh, 16));

    float mxl = mx * LOG2E;
    float t0 = __fmaf_rn(v.x, LOG2E, -mxl);
    float t1 = __fmaf_rn(v.y, LOG2E, -mxl);
    float t2 = __fmaf_rn(v.z, LOG2E, -mxl);
    float t3 = __fmaf_rn(v.w, LOG2E, -mxl);
    float x0 = __builtin_amdgcn_exp2f(t0);
    float x1 = __builtin_amdgcn_exp2f(t1);
    float x2 = __builtin_amdgcn_exp2f(t2);
    float x3 = __builtin_amdgcn_exp2f(t3);

    float z = (x0 + x1) + (x2 + x3);
    #pragma unroll
    for (int sh = 1; sh < 16; sh <<= 1) z += __shfl_xor(z, sh, 16);

    float lz = __builtin_amdgcn_logf(z);               // log2(z)
    float rz = __builtin_amdgcn_exp2f(-lz);            // 1/z (no div sequence)
    float zq = __builtin_amdgcn_exp2f(-QQ * lz);       // z^-1.2

    float w0 = x0*rz, w1 = x1*rz, w2 = x2*rz, w3 = x3*rz;
    float c0 = fmaxf(w0, EPS), c1 = fmaxf(w1, EPS);
    float c2 = fmaxf(w2, EPS), c3 = fmaxf(w3, EPS);
    float q0 = fmaxf(__builtin_amdgcn_exp2f(QQ*t0)*zq, EPSQ);
    float q1 = fmaxf(__builtin_amdgcn_exp2f(QQ*t1)*zq, EPSQ);
    float q2 = fmaxf(__builtin_amdgcn_exp2f(QQ*t2)*zq, EPSQ);
    float q3 = fmaxf(__builtin_amdgcn_exp2f(QQ*t3)*zq, EPSQ);

    float rcl = (c0+c1)+(c2+c3);
    float rql = (q0+q1)+(q2+q3);
    if (valid) { clipA += rcl; clipqA += rql; }

    float rcq = rql;
    #pragma unroll
    for (int sh = 1; sh < 16; sh <<= 1) rcq += __shfl_xor(rcq, sh, 16);

    ea0 = __fmaf_rn(w0, msc, ea0);
    ea1 = __fmaf_rn(w1, msc, ea1);
    ea2 = __fmaf_rn(w2, msc, ea2);
    ea3 = __fmaf_rn(w3, msc, ea3);

    // rare path screen: flag needs rcq >= 0.7 * rc^1.2 and rc >= 1
    bool pre = valid && (msc != 0.f) && (rcq >= 0.699f);
    unsigned long long balpre = __ballot(pre ? 1 : 0);
    if (balpre) {
        float rc = rcl;
        #pragma unroll
        for (int sh = 1; sh < 16; sh <<= 1) rc += __shfl_xor(rc, sh, 16);
        float ent = (1.f - rcq * __builtin_amdgcn_exp2f(-QQ * __builtin_amdgcn_logf(rc))) * 5.f;
        bool flag = pre && (ent < 1.5f);
        unsigned long long bal = __ballot(flag ? 1 : 0);
        #pragma unroll 1
        for (int g = 0; g < 4; ++g) {
            if ((bal >> (g * 16)) & 0xFFFFull) {
                if (grp == g) {
                    float wl[4] = {w0, w1, w2, w3};
                    int   rank[4] = {0, 0, 0, 0};
                    float cum[4]  = {wl[0], wl[1], wl[2], wl[3]};
                    int base4 = s << 2;
                    #pragma unroll 1
                    for (int j = 0; j < 16; ++j) {
                        float uj[4];
                        uj[0] = __shfl(w0, j, 16);
                        uj[1] = __shfl(w1, j, 16);
                        uj[2] = __shfl(w2, j, 16);
                        uj[3] = __shfl(w3, j, 16);
                        #pragma unroll
                        for (int m = 0; m < 4; ++m) {
                            int ej = (j << 2) + m;
                            #pragma unroll
                            for (int k = 0; k < 4; ++k) {
                                int ek = base4 + k;
                                bool before = (uj[m] > wl[k]) || (uj[m] == wl[k] && ej < ek);
                                if (before) { rank[k]++; cum[k] += uj[m]; }
                            }
                        }
                    }
                    #pragma unroll
                    for (int k = 0; k < 4; ++k)
                        if (cum[k] > 0.75f && rank[k] >= 2)
                            atomicAdd(&acc[64 + base4 + k], wl[k]);   // mscale==1 here
                }
            }
        }
    }
}

#define LOAD_TILE(V0, V1, V2, V3, M, RB) do {                                   \
    long long r0_ = (RB)+0 < N ? (RB)+0 : N-1;                                  \
    long long r1_ = (RB)+1 < N ? (RB)+1 : N-1;                                  \
    long long r2_ = (RB)+2 < N ? (RB)+2 : N-1;                                  \
    long long r3_ = (RB)+3 < N ? (RB)+3 : N-1;                                  \
    V0 = *((const float4*)(G + (r0_ << 6)) + s);                                \
    V1 = *((const float4*)(G + (r1_ << 6)) + s);                                \
    V2 = *((const float4*)(G + (r2_ << 6)) + s);                                \
    V3 = *((const float4*)(G + (r3_ << 6)) + s);                                \
    long long mr_ = (RB) < N ? (RB) : N-1;                                      \
    int mi_ = maskPow2 ? (int)(mr_ & (long long)(maskN-1))                      \
                       : (int)(mr_ % (long long)maskN);                         \
    mi_ &= ~3;                                                                  \
    M = *(const int4*)(am + mi_);                                               \
} while (0)

__global__ __launch_bounds__(256)
void moe_main(const float* __restrict__ G, const int* __restrict__ am,
              long long N, int maskN, int maskPow2, float* __restrict__ acc)
{
    __shared__ float sm[4][66];
    const int t    = threadIdx.x;
    const int lane = t & 63;
    const int wv   = t >> 6;
    const int s    = lane & 15;   // expert quad: experts 4s..4s+3
    const int grp  = lane >> 4;
    const long long tiles = (N + 63) >> 6;              // 64 rows per block-tile
    const long long roff  = (long long)(wv * 16 + grp * 4);
    const long long gstep = (long long)gridDim.x;

    float ea0=0.f, ea1=0.f, ea2=0.f, ea3=0.f, clipA=0.f, clipqA=0.f;

    long long tl = blockIdx.x;
    if (tl < tiles) {
        long long rb = tl * 64 + roff;
        float4 Av0, Av1, Av2, Av3; int4 Am;
        LOAD_TILE(Av0, Av1, Av2, Av3, Am, rb);

        while (tl < tiles) {
            long long tn  = tl + gstep;
            long long tnc = (tn < tiles) ? tn : tl;     // last iter: harmless reload
            long long rbn = tnc * 64 + roff;

            // issue next tile's loads BEFORE computing current (latency hidden)
            float4 Bv0, Bv1, Bv2, Bv3; int4 Bm;
            LOAD_TILE(Bv0, Bv1, Bv2, Bv3, Bm, rbn);

            pass_row(Av0, (rb+0 < N) ? (float)Am.x : 0.f, rb+0 < N, s, grp,
                     ea0, ea1, ea2, ea3, clipA, clipqA, acc);
            pass_row(Av1, (rb+1 < N) ? (float)Am.y : 0.f, rb+1 < N, s, grp,
                     ea0, ea1, ea2, ea3, clipA, clipqA, acc);
            pass_row(Av2, (rb+2 < N) ? (float)Am.z : 0.f, rb+2 < N, s, grp,
                     ea0, ea1, ea2, ea3, clipA, clipqA, acc);
            pass_row(Av3, (rb+3 < N) ? (float)Am.w : 0.f, rb+3 < N, s, grp,
                     ea0, ea1, ea2, ea3, clipA, clipqA, acc);

            Av0 = Bv0; Av1 = Bv1; Av2 = Bv2; Av3 = Bv3; Am = Bm;
            rb = rbn; tl = tn;
        }
    }

    // epilogue: reduce per-expert sums across the 4 row-groups of each wave
    ea0 += __shfl_xor(ea0, 16, 64); ea0 += __shfl_xor(ea0, 32, 64);
    ea1 += __shfl_xor(ea1, 16, 64); ea1 += __shfl_xor(ea1, 32, 64);
    ea2 += __shfl_xor(ea2, 16, 64); ea2 += __shfl_xor(ea2, 32, 64);
    ea3 += __shfl_xor(ea3, 16, 64); ea3 += __shfl_xor(ea3, 32, 64);
    #pragma unroll
    for (int sh = 1; sh <= 32; sh <<= 1) {
        clipA  += __shfl_xor(clipA,  sh, 64);
        clipqA += __shfl_xor(clipqA, sh, 64);
    }
    if (grp == 0) {
        sm[wv][(s << 2) + 0] = ea0;
        sm[wv][(s << 2) + 1] = ea1;
        sm[wv][(s << 2) + 2] = ea2;
        sm[wv][(s << 2) + 3] = ea3;
    }
    if (lane == 0) { sm[wv][64] = clipA; sm[wv][65] = clipqA; }
    __syncthreads();
    if (t < 64) {
        float v = (sm[0][t] + sm[1][t]) + (sm[2][t] + sm[3][t]);
        atomicAdd(&acc[t], v);
    }
    if (t == 0) {
        atomicAdd(&acc[128], (sm[0][64] + sm[1][64]) + (sm[2][64] + sm[3][64]));
        atomicAdd(&acc[129], (sm[0][65] + sm[1][65]) + (sm[2][65] + sm[3][65]));
    }
}

__global__ void finalize(const float* __restrict__ acc, const int* __restrict__ am,
                         int maskN, int layers, float* __restrict__ out) {
    __shared__ float red[256];
    int t = threadIdx.x;

    float ms = 0.f;
    for (int i = t; i < maskN; i += 256) ms += (float)am[i];
    red[t] = ms; __syncthreads();
    for (int s = 128; s >= 1; s >>= 1) { if (t < s) red[t] += red[t + s]; __syncthreads(); }
    float denom = red[0] * (float)layers;
    __syncthreads();

    float p = 0.f;
    if (t < 64) {
        float o   = acc[t];
        float tok = o - acc[64 + t];
        p = tok * o;
    }
    red[t] = p; __syncthreads();
    for (int s = 128; s >= 1; s >>= 1) { if (t < s) red[t] += red[t + s]; __syncthreads(); }

    if (t == 0) {
        float lb    = 64.f * red[0] / (denom * denom);
        float clip  = acc[128], clipq = acc[129];
        float ent   = (1.f - clipq * __builtin_amdgcn_exp2f(-QQ * __builtin_amdgcn_logf(clip))) * 5.f;
        out[0] = 1e-3f * ent + 1e-3f * lb;
    }
}

extern "C" void kernel_launch(void* const* d_in, const int* in_sizes, int n_in,
                              void* d_out, int out_size, void* d_ws, size_t ws_size,
                              hipStream_t stream) {
    const float* G  = (const float*)d_in[0];
    const int*   am = (const int*)d_in[1];
    long long NE = in_sizes[0];
    long long N  = NE / 64;
    int maskN    = in_sizes[1];
    int layers   = (int)(N / (long long)maskN);
    int maskPow2 = ((maskN & (maskN - 1)) == 0) ? 1 : 0;
    float* acc = (float*)d_ws;   // 130 floats

    long long tiles = (N + 63) >> 6;
    int grid = (int)(tiles < 1024 ? tiles : 1024);   // ~4 blocks/CU resident, 16 tiles each

    hipLaunchKernelGGL(zero_acc, dim3(1), dim3(256), 0, stream, acc);
    hipLaunchKernelGGL(moe_main, dim3(grid), dim3(256), 0, stream,
                       G, am, N, maskN, maskPow2, acc);
    hipLaunchKernelGGL(finalize, dim3(1), dim3(256), 0, stream,
                       acc, am, maskN, layers, (float*)d_out);
}